// Round 12
// baseline (1451.177 us; speedup 1.0000x reference)
//
#include <hip/hip_runtime.h>
#include <math.h>

#define NPTS 10000
#define NP   512    // npoint
#define NS   64     // nsample
#define NTOK 513    // 1 + NP
#define DIM  512
#define NHEADS 8
#define DH   64
#define DEPTH 6
#define SAD  256
#define MLPD 1024
#define EPSV 1e-5f
#define PEB  2057   // ceil(2*NTOK*NTOK / 256)

typedef float  f32x2  __attribute__((ext_vector_type(2)));
typedef float  f32x4  __attribute__((ext_vector_type(4)));
typedef __bf16 bf16x8 __attribute__((ext_vector_type(8)));
typedef unsigned short u16x4 __attribute__((ext_vector_type(4)));
typedef unsigned short u16x8 __attribute__((ext_vector_type(8)));

__device__ __forceinline__ unsigned short f2bf(float x) {
    unsigned u = __float_as_uint(x);
    unsigned r = u + 0x7fffu + ((u >> 16) & 1u);   // RNE
    return (unsigned short)(r >> 16);
}
__device__ __forceinline__ bf16x8 bf8_from_f32(const float* p) {
    u16x8 h;
    #pragma unroll
    for (int e = 0; e < 8; e++) h[e] = f2bf(p[e]);
    return *(bf16x8*)&h;
}

// ---------------- block reduce helper (256-thread blocks) ----------------
__device__ __forceinline__ float blk_sum256(float v, float* red) {
    #pragma unroll
    for (int off = 32; off; off >>= 1) v += __shfl_down(v, off);
    __syncthreads();
    if ((threadIdx.x & 63) == 0) red[threadIdx.x >> 6] = v;
    __syncthreads();
    return red[0] + red[1] + red[2] + red[3];
}

// ---------------- FPS (blocks 0,1) + weight convert (blocks 2+) ------------
// FPS: serial chain minimized. Per-thread 20-way argmax via compare tree
// (slot order == index order so ties need no index cmp). Wave argmax via
// DPP (VALU, ~120cy) instead of ds_bpermute butterfly (~1300cy): row_shr
// 1/2/4/8 + row_bcast15/31, result in lane 63. ONE barrier/iter; winner
// coords prefetched via uniform loads before the barrier.
__global__ __launch_bounds__(512, 1) void fps_wconv_kernel(
        const float* __restrict__ f, float* __restrict__ cent3,
        const float* __restrict__ qkv_w, unsigned short* __restrict__ qkvT,
        const float* __restrict__ out_w, unsigned short* __restrict__ outT,
        const float* __restrict__ ff_w1, unsigned short* __restrict__ ff1T,
        const float* __restrict__ ff_w2, unsigned short* __restrict__ ff2T) {
    #pragma clang fp contract(off)
    __shared__ unsigned long long spk[2][8];
    __shared__ float scx[2][8], scy[2][8], scz[2][8];
    __shared__ unsigned short tl[64][65];

    if (blockIdx.x >= 2) {
        // ---------- weight convert+transpose (64x64 tile, 512 thr) ----------
        int id = blockIdx.x - 2;
        const float* Ws; unsigned short* Wd; int K, N, tn, per;
        if (id < 1152)      { Ws = qkv_w; Wd = qkvT; K = 512;  N = 1536; tn = 24; per = 192; }
        else if (id < 1536) { id -= 1152; Ws = out_w; Wd = outT; K = 512; N = 512; tn = 8;  per = 64;  }
        else if (id < 2304) { id -= 1536; Ws = ff_w1; Wd = ff1T; K = 512; N = 1024; tn = 16; per = 128; }
        else                { id -= 2304; Ws = ff_w2; Wd = ff2T; K = 1024; N = 512; tn = 8;  per = 128; }
        const int l = id / per, rem = id % per;
        const int n0 = (rem % tn) * 64, k0 = (rem / tn) * 64;
        Ws += (size_t)l * K * N;
        Wd += (size_t)l * K * N;
        const int ty = threadIdx.x >> 4, c4 = (threadIdx.x & 15) * 4;   // ty 0..31
        #pragma unroll
        for (int i = 0; i < 2; i++) {
            int r = ty + 32 * i;
            f32x4 v = *(const f32x4*)(Ws + (size_t)(k0 + r) * N + n0 + c4);
            tl[c4 + 0][r] = f2bf(v.x);
            tl[c4 + 1][r] = f2bf(v.y);
            tl[c4 + 2][r] = f2bf(v.z);
            tl[c4 + 3][r] = f2bf(v.w);
        }
        __syncthreads();
        #pragma unroll
        for (int i = 0; i < 2; i++) {
            int r = ty + 32 * i;
            u16x4 hv = { tl[r][c4], tl[r][c4 + 1], tl[r][c4 + 2], tl[r][c4 + 3] };
            *(u16x4*)(Wd + (size_t)(n0 + r) * K + k0 + c4) = hv;
        }
        return;
    }

    // ---------- FPS ----------
    const int b = blockIdx.x;
    const float* fx = f + (size_t)b * 3 * NPTS;
    const float* fy = fx + NPTS;
    const float* fz = fx + 2 * NPTS;
    const int t = threadIdx.x;
    const int wv = t >> 6, lane = t & 63;

    f32x2 px[10], py[10], pz[10], dist[10];
    #pragma unroll
    for (int q = 0; q < 10; q++) {
        #pragma unroll
        for (int e = 0; e < 2; e++) {
            int p = t + (2 * q + e) * 512;
            if (p < NPTS) { px[q][e] = fx[p]; py[q][e] = fy[p]; pz[q][e] = fz[p]; dist[q][e] = 1e10f; }
            else          { px[q][e] = 0.f;  py[q][e] = 0.f;  pz[q][e] = 0.f;  dist[q][e] = -1.0f; }
        }
    }
    if (t == 0) {
        float* c0 = cent3 + (size_t)b * NTOK * 3;
        c0[0] = 0.f; c0[1] = 0.f; c0[2] = 0.f;
    }
    float cx = fx[0], cy = fy[0], cz = fz[0];

    for (int it = 0; it < NP; ++it) {
        if (t == 0) {
            float* c = cent3 + (size_t)(b * NTOK + 1 + it) * 3;
            c[0] = cx; c[1] = cy; c[2] = cz;
        }
        const f32x2 c2x = {cx, cx}, c2y = {cy, cy}, c2z = {cz, cz};
        float av[20]; unsigned ai[20];
        #pragma unroll
        for (int q = 0; q < 10; q++) {
            f32x2 dx = px[q] - c2x;
            f32x2 dy = py[q] - c2y;
            f32x2 dz = pz[q] - c2z;
            f32x2 s1 = dx * dx;
            f32x2 s2 = dy * dy;
            f32x2 s3 = dz * dz;
            f32x2 d  = (s1 + s2) + s3;
            f32x2 nd = __builtin_elementwise_min(dist[q], d);
            dist[q] = nd;
            av[2 * q]     = nd.x; ai[2 * q]     = (unsigned)(t + (2 * q) * 512);
            av[2 * q + 1] = nd.y; ai[2 * q + 1] = (unsigned)(t + (2 * q + 1) * 512);
        }
        // in-thread argmax tree; slots ordered by index so '>' keeps first-max
        #define CMB(a, bq) if (av[bq] > av[a]) { av[a] = av[bq]; ai[a] = ai[bq]; }
        #pragma unroll
        for (int i = 0; i < 10; i++) CMB(i, i + 10)
        #pragma unroll
        for (int i = 0; i < 5; i++) CMB(i, i + 5)
        CMB(0, 1) CMB(2, 3) CMB(0, 2) CMB(0, 4)
        #undef CMB
        float bv = av[0]; unsigned bi = ai[0];
        // wave argmax via DPP (lexicographic: larger dist, then smaller idx)
        #define DSTEP(CTRL, RM) { \
            int _ov = __builtin_amdgcn_update_dpp(__float_as_int(bv), __float_as_int(bv), CTRL, RM, 0xF, false); \
            int _oi = __builtin_amdgcn_update_dpp((int)bi, (int)bi, CTRL, RM, 0xF, false); \
            float ov = __int_as_float(_ov); unsigned oi = (unsigned)_oi; \
            bool take = (ov > bv) || (ov == bv && oi < bi); \
            bv = take ? ov : bv; bi = take ? oi : bi; \
        }
        DSTEP(0x111, 0xF)   // row_shr:1
        DSTEP(0x112, 0xF)   // row_shr:2
        DSTEP(0x114, 0xF)   // row_shr:4
        DSTEP(0x118, 0xF)   // row_shr:8
        DSTEP(0x142, 0xA)   // row_bcast:15 -> rows 1,3
        DSTEP(0x143, 0xC)   // row_bcast:31 -> rows 2,3
        #undef DSTEP
        unsigned wbi = (unsigned)__builtin_amdgcn_readlane((int)bi, 63);
        float    wbv = __int_as_float(__builtin_amdgcn_readlane(__float_as_int(bv), 63));
        // wave candidate coords via uniform scalar loads (overlap the barrier)
        float wx = fx[wbi], wy = fy[wbi], wz = fz[wbi];
        unsigned long long best = ((unsigned long long)__float_as_uint(wbv) << 32)
                                | (unsigned long long)(~wbi);
        const int cur = it & 1;
        if (lane == 0) {
            spk[cur][wv] = best;
            scx[cur][wv] = wx; scy[cur][wv] = wy; scz[cur][wv] = wz;
        }
        __syncthreads();
        unsigned long long g = spk[cur][0]; int bw = 0;
        #pragma unroll
        for (int w = 1; w < 8; w++) {
            unsigned long long o = spk[cur][w];
            if (o > g) { g = o; bw = w; }
        }
        cx = scx[cur][bw]; cy = scy[cur][bw]; cz = scz[cur][bw];
    }
}

// ---------------- ballmlp (blocks < 2*NP) + pe bias (blocks >= 2*NP) --------
__global__ __launch_bounds__(256) void ballmlp_pe_kernel(
        const float* __restrict__ f, const float* __restrict__ cent3,
        const float* __restrict__ w0, const float* __restrict__ b0,
        const float* __restrict__ g0, const float* __restrict__ be0,
        const float* __restrict__ m0, const float* __restrict__ v0,
        const float* __restrict__ w1, const float* __restrict__ b1,
        const float* __restrict__ g1, const float* __restrict__ be1,
        const float* __restrict__ m1, const float* __restrict__ v1,
        const float* __restrict__ w2, const float* __restrict__ b2,
        const float* __restrict__ g2, const float* __restrict__ be2,
        const float* __restrict__ m2, const float* __restrict__ v2,
        float* __restrict__ featb,
        const float* __restrict__ pw1_, const float* __restrict__ pb1_,
        const float* __restrict__ pw2_, const float* __restrict__ pb2_,
        float* __restrict__ pebuf) {
    if (blockIdx.x >= 2 * NP) {
        // ---------- pe bias: fused 3->64(relu)->1, all layers ----------
        const int id = blockIdx.x - 2 * NP;
        const int l = id / PEB, rem = id % PEB;
        const float* pw1 = pw1_ + l * 192;
        const float* pb1 = pb1_ + l * 64;
        const float* pw2 = pw2_ + l * 64;
        const long total = 2L * NTOK * NTOK;
        long gid = (long)rem * 256 + threadIdx.x;
        if (gid >= total) return;
        int j = (int)(gid % NTOK);
        long r = gid / NTOK;
        int i = (int)(r % NTOK);
        int b = (int)(r / NTOK);
        const float* ci = cent3 + (size_t)(b * NTOK + i) * 3;
        const float* cj = cent3 + (size_t)(b * NTOK + j) * 3;
        float d0 = ci[0] - cj[0], d1 = ci[1] - cj[1], d2 = ci[2] - cj[2];
        float acc = pb2_[l];
        #pragma unroll 8
        for (int c = 0; c < 64; c++) {
            float tv = pw1[c * 3] * d0 + pw1[c * 3 + 1] * d1 + pw1[c * 3 + 2] * d2 + pb1[c];
            acc += pw2[c] * fmaxf(tv, 0.f);
        }
        pebuf[(size_t)l * total + gid] = acc;
        return;
    }

    // ---------- ballmlp ----------
    const int bs = blockIdx.x;
    const int b = bs / NP, s = bs % NP;
    const int tid = threadIdx.x;
    const int wv = tid >> 6, lane = tid & 63;
    const int fr = lane & 15, fq = lane >> 4;

    __shared__ int sidx[NS];
    __shared__ alignas(16) unsigned short Xl[64][8];
    __shared__ alignas(16) unsigned short H1[64][72];
    __shared__ alignas(16) unsigned short H2[64][72];

    const float* fx = f + (size_t)b * 3 * NPTS;
    const float* fy = fx + NPTS;
    const float* fz = fx + 2 * NPTS;
    const float* c  = cent3 + (size_t)(b * NTOK + 1 + s) * 3;
    const float nx = c[0], ny = c[1], nz = c[2];

    const int c1 = 16 * wv + fr;
    const float sc0 = g0[c1] / sqrtf(v0[c1] + EPSV);
    const float off0 = (b0[c1] - m0[c1]) * sc0 + be0[c1];
    const float sc1 = g1[c1] / sqrtf(v1[c1] + EPSV);
    const float off1 = (b1[c1] - m1[c1]) * sc1 + be1[c1];

    u16x8 b0h = {0,0,0,0,0,0,0,0};
    if (fq == 0) {
        const float* wr = w0 + c1 * 6;
        #pragma unroll
        for (int e = 0; e < 6; e++) b0h[e] = f2bf(wr[e]);
    }
    bf16x8 bf0 = *(bf16x8*)&b0h;
    bf16x8 bf1[2];
    #pragma unroll
    for (int ks = 0; ks < 2; ks++)
        bf1[ks] = bf8_from_f32(w1 + (size_t)c1 * 64 + ks * 32 + fq * 8);

    if (wv == 0) {
        const float nn = __fadd_rn(__fadd_rn(__fmul_rn(nx, nx), __fmul_rn(ny, ny)), __fmul_rn(nz, nz));
        int cnt = 0, first = -1;
        for (int base = 0; base < NPTS; base += 64) {
            const int p = base + lane;
            bool valid = false;
            if (p < NPTS) {
                float x = fx[p], y = fy[p], z = fz[p];
                float pp = __fadd_rn(__fadd_rn(__fmul_rn(x, x), __fmul_rn(y, y)), __fmul_rn(z, z));
                float dt = __fadd_rn(__fadd_rn(__fmul_rn(nx, x), __fmul_rn(ny, y)), __fmul_rn(nz, z));
                float sq = __fsub_rn(__fadd_rn(nn, pp), __fmul_rn(2.0f, dt));
                valid = !(sq > 0.04f);
            }
            unsigned long long m = __ballot(valid);
            if (first < 0 && m) first = base + __builtin_ctzll(m);
            int pos = cnt + __popcll(m & ((1ull << lane) - 1ull));
            if (valid && pos < NS) sidx[pos] = p;
            cnt += __popcll(m);
            if (cnt >= NS) break;
        }
        for (int pos = cnt + lane; pos < NS; pos += 64) sidx[pos] = first;
    }
    __syncthreads();

    if (tid < 64) {
        const int p = sidx[tid];
        float i3 = fx[p], i4 = fy[p], i5 = fz[p];
        u16x8 xv;
        xv[0] = f2bf(i3 - nx); xv[1] = f2bf(i4 - ny); xv[2] = f2bf(i5 - nz);
        xv[3] = f2bf(i3); xv[4] = f2bf(i4); xv[5] = f2bf(i5);
        xv[6] = 0; xv[7] = 0;
        *(u16x8*)(&Xl[tid][0]) = xv;
    }
    __syncthreads();

    const u16x8 z8 = {0,0,0,0,0,0,0,0};
    const bf16x8 zf = *(const bf16x8*)&z8;

    #pragma unroll
    for (int m = 0; m < 4; m++) {
        bf16x8 af = (fq == 0) ? *(const bf16x8*)(&Xl[m * 16 + fr][0]) : zf;
        f32x4 d = (f32x4){0.f, 0.f, 0.f, 0.f};
        d = __builtin_amdgcn_mfma_f32_16x16x32_bf16(af, bf0, d, 0, 0, 0);
        #pragma unroll
        for (int j = 0; j < 4; j++) {
            float v = fmaxf(d[j] * sc0 + off0, 0.f);
            H1[m * 16 + fq * 4 + j][16 * wv + fr] = f2bf(v);
        }
    }
    __syncthreads();

    #pragma unroll
    for (int m = 0; m < 4; m++) {
        f32x4 d = (f32x4){0.f, 0.f, 0.f, 0.f};
        #pragma unroll
        for (int ks = 0; ks < 2; ks++) {
            bf16x8 af = *(const bf16x8*)(&H1[m * 16 + fr][ks * 32 + fq * 8]);
            d = __builtin_amdgcn_mfma_f32_16x16x32_bf16(af, bf1[ks], d, 0, 0, 0);
        }
        #pragma unroll
        for (int j = 0; j < 4; j++) {
            float v = fmaxf(d[j] * sc1 + off1, 0.f);
            H2[m * 16 + fq * 4 + j][16 * wv + fr] = f2bf(v);
        }
    }
    __syncthreads();

    bf16x8 af2[4][2];
    #pragma unroll
    for (int m = 0; m < 4; m++)
        #pragma unroll
        for (int ks = 0; ks < 2; ks++)
            af2[m][ks] = *(const bf16x8*)(&H2[m * 16 + fr][ks * 32 + fq * 8]);

    float* outp = featb + (size_t)bs * SAD;
    #pragma unroll
    for (int t = 0; t < 4; t++) {
        const int c2 = 64 * wv + 16 * t + fr;
        const float sc2 = g2[c2] / sqrtf(v2[c2] + EPSV);
        const float off2 = (b2[c2] - m2[c2]) * sc2 + be2[c2];
        bf16x8 bf2[2];
        #pragma unroll
        for (int ks = 0; ks < 2; ks++)
            bf2[ks] = bf8_from_f32(w2 + (size_t)c2 * 64 + ks * 32 + fq * 8);
        float mx = -INFINITY;
        #pragma unroll
        for (int m = 0; m < 4; m++) {
            f32x4 d = (f32x4){0.f, 0.f, 0.f, 0.f};
            d = __builtin_amdgcn_mfma_f32_16x16x32_bf16(af2[m][0], bf2[0], d, 0, 0, 0);
            d = __builtin_amdgcn_mfma_f32_16x16x32_bf16(af2[m][1], bf2[1], d, 0, 0, 0);
            #pragma unroll
            for (int j = 0; j < 4; j++)
                mx = fmaxf(mx, fmaxf(d[j] * sc2 + off2, 0.f));
        }
        mx = fmaxf(mx, __shfl_xor(mx, 16));
        mx = fmaxf(mx, __shfl_xor(mx, 32));
        if (fq == 0) outp[c2] = mx;
    }
}

// ---------------- lift (259->512) + LayerNorm (+cls rows, blocks 0,1) -------
__global__ __launch_bounds__(256) void lift_ln_kernel(const float* __restrict__ cent3,
                                                      const float* __restrict__ featb,
                                                      const float* __restrict__ lw,
                                                      const float* __restrict__ lb,
                                                      const float* __restrict__ lg,
                                                      const float* __restrict__ lbeta,
                                                      const float* __restrict__ cls,
                                                      float* __restrict__ x) {
    const int t = threadIdx.x;
    if (blockIdx.x < 2) {
        int b = blockIdx.x;
        x[(size_t)(b * NTOK) * DIM + t]       = cls[t];
        x[(size_t)(b * NTOK) * DIM + t + 256] = cls[t + 256];
        return;
    }
    const int bs = blockIdx.x - 2;
    const int b = bs / NP, s = bs % NP;
    __shared__ float si[259];
    __shared__ float sy[512];
    __shared__ float red[4];
    if (t < 3) si[t] = cent3[(size_t)(b * NTOK + 1 + s) * 3 + t];
    si[3 + t] = featb[(size_t)bs * SAD + t];
    __syncthreads();
    for (int o = t; o < DIM; o += 256) {
        const float* wr = lw + (size_t)o * 259;
        float acc = lb[o];
        for (int ci = 0; ci < 259; ci++) acc += wr[ci] * si[ci];
        sy[o] = acc;
    }
    __syncthreads();
    float tot  = blk_sum256(sy[t] + sy[t + 256], red);
    float mean = tot * (1.0f / 512.0f);
    float d0 = sy[t] - mean, d1 = sy[t + 256] - mean;
    float var = blk_sum256(d0 * d0 + d1 * d1, red) * (1.0f / 512.0f);
    float inv = 1.0f / sqrtf(var + EPSV);
    float* xr = x + (size_t)(b * NTOK + 1 + s) * DIM;
    xr[t]       = d0 * inv * lg[t]       + lbeta[t];
    xr[t + 256] = d1 * inv * lg[t + 256] + lbeta[t + 256];
}

// ---------------- LayerNorm rows of [2*NTOK, 512]; bf16 output --------------
__global__ __launch_bounds__(256) void ln_kernel(const float* __restrict__ xin,
                                                 const float* __restrict__ g,
                                                 const float* __restrict__ beta,
                                                 unsigned short* __restrict__ y) {
    const int r = blockIdx.x;
    const float* xr = xin + (size_t)r * DIM;
    const int t = threadIdx.x;
    float a0 = xr[t], a1 = xr[t + 256];
    __shared__ float red[4];
    float mean = blk_sum256(a0 + a1, red) * (1.0f / 512.0f);
    float d0 = a0 - mean, d1 = a1 - mean;
    float var = blk_sum256(d0 * d0 + d1 * d1, red) * (1.0f / 512.0f);
    float inv = 1.0f / sqrtf(var + EPSV);
    unsigned short* yr = y + (size_t)r * DIM;
    yr[t]       = f2bf(d0 * inv * g[t]       + beta[t]);
    yr[t + 256] = f2bf(d1 * inv * g[t + 256] + beta[t + 256]);
}

// ---------------- MFMA flash attention (bf16 qkv in, bf16 out) --------------
__global__ __launch_bounds__(256) void attn_mfma_kernel(const unsigned short* __restrict__ qkv,
                                                        const float* __restrict__ pebuf,
                                                        unsigned short* __restrict__ obuf) {
    __shared__ alignas(16) unsigned short Qs[64][72];
    __shared__ alignas(16) unsigned short Ks[64][72];
    __shared__ alignas(16) unsigned short Vt[64][72];
    __shared__ alignas(16) unsigned short Ps[64][72];

    const int ti = blockIdx.x;           // 0..8
    const int bh = blockIdx.y;           // 0..15
    const int b = bh >> 3, h = bh & 7;
    const int i0 = ti * 64;
    const int tid = threadIdx.x;
    const int w = tid >> 6, lane = tid & 63;
    const int fr = lane & 15, fq = lane >> 4;
    const int fko = fq * 8;

    const unsigned short* qbase = qkv + (size_t)b * NTOK * (3 * DIM) + h * DH;
    const int sr = tid >> 2, sc = (tid & 3) * 16;

    {
        int i = i0 + sr;
        u16x8 v0 = {0,0,0,0,0,0,0,0}, v1 = {0,0,0,0,0,0,0,0};
        if (i < NTOK) {
            v0 = *(const u16x8*)(qbase + (size_t)i * (3 * DIM) + sc);
            v1 = *(const u16x8*)(qbase + (size_t)i * (3 * DIM) + sc + 8);
        }
        *(u16x8*)(&Qs[sr][sc]) = v0;
        *(u16x8*)(&Qs[sr][sc + 8]) = v1;
    }

    float mrow[4], lrow[4];
    f32x4 od[4];
    #pragma unroll
    for (int r = 0; r < 4; r++) { mrow[r] = -INFINITY; lrow[r] = 0.f; }
    #pragma unroll
    for (int dt = 0; dt < 4; dt++) od[dt] = (f32x4){0.f, 0.f, 0.f, 0.f};

    const unsigned short* kbase = qkv + (size_t)b * NTOK * (3 * DIM) + DIM + h * DH;
    const unsigned short* vbase = qkv + (size_t)b * NTOK * (3 * DIM) + 2 * DIM + h * DH;

    for (int jc = 0; jc < 9; jc++) {
        const int j0 = jc * 64;
        const int wj = (NTOK - j0) < 64 ? (NTOK - j0) : 64;   // 64 or 1
        __syncthreads();
        if (sr < wj) {
            const unsigned short* kp = kbase + (size_t)(j0 + sr) * (3 * DIM) + sc;
            const unsigned short* vp = vbase + (size_t)(j0 + sr) * (3 * DIM) + sc;
            u16x8 k0 = *(const u16x8*)(kp);
            u16x8 k1 = *(const u16x8*)(kp + 8);
            *(u16x8*)(&Ks[sr][sc]) = k0;
            *(u16x8*)(&Ks[sr][sc + 8]) = k1;
            u16x8 q0 = *(const u16x8*)(vp);
            u16x8 q1 = *(const u16x8*)(vp + 8);
            #pragma unroll
            for (int e = 0; e < 8; e++) {
                Vt[sc + e][sr] = q0[e];
                Vt[sc + 8 + e][sr] = q1[e];
            }
        } else {
            u16x8 z = {0,0,0,0,0,0,0,0};
            *(u16x8*)(&Ks[sr][sc]) = z;
            *(u16x8*)(&Ks[sr][sc + 8]) = z;
            #pragma unroll
            for (int e = 0; e < 16; e++) Vt[sc + e][sr] = 0;
        }
        __syncthreads();

        bf16x8 qf0 = *(const bf16x8*)(&Qs[16 * w + fr][fko]);
        bf16x8 qf1 = *(const bf16x8*)(&Qs[16 * w + fr][fko + 32]);
        f32x4 sa[4];
        #pragma unroll
        for (int jt = 0; jt < 4; jt++) {
            f32x4 acc = (f32x4){0.f, 0.f, 0.f, 0.f};
            bf16x8 kf0 = *(const bf16x8*)(&Ks[jt * 16 + fr][fko]);
            bf16x8 kf1 = *(const bf16x8*)(&Ks[jt * 16 + fr][fko + 32]);
            acc = __builtin_amdgcn_mfma_f32_16x16x32_bf16(qf0, kf0, acc, 0, 0, 0);
            acc = __builtin_amdgcn_mfma_f32_16x16x32_bf16(qf1, kf1, acc, 0, 0, 0);
            sa[jt] = acc;
        }

        float sv[4][4];
        float cm[4] = {-INFINITY, -INFINITY, -INFINITY, -INFINITY};
        #pragma unroll
        for (int jt = 0; jt < 4; jt++) {
            int jl = jt * 16 + fr;
            int jg = j0 + jl; if (jg > NTOK - 1) jg = NTOK - 1;
            #pragma unroll
            for (int r = 0; r < 4; r++) {
                int i = i0 + 16 * w + fq * 4 + r; if (i > NTOK - 1) i = NTOK - 1;
                float pe = pebuf[((size_t)b * NTOK + i) * NTOK + jg];
                float s = (sa[jt][r] + pe) * 0.125f;
                s = (jl < wj) ? s : -INFINITY;
                sv[jt][r] = s;
                cm[r] = fmaxf(cm[r], s);
            }
        }
        #pragma unroll
        for (int off = 1; off < 16; off <<= 1) {
            #pragma unroll
            for (int r = 0; r < 4; r++) cm[r] = fmaxf(cm[r], __shfl_xor(cm[r], off));
        }
        float fac[4], rs[4];
        #pragma unroll
        for (int r = 0; r < 4; r++) {
            float mn = fmaxf(mrow[r], cm[r]);
            fac[r] = __expf(mrow[r] - mn);
            mrow[r] = mn;
            rs[r] = 0.f;
        }
        #pragma unroll
        for (int jt = 0; jt < 4; jt++) {
            #pragma unroll
            for (int r = 0; r < 4; r++) {
                float p = __expf(sv[jt][r] - mrow[r]);
                rs[r] += p;
                Ps[16 * w + fq * 4 + r][jt * 16 + fr] = f2bf(p);
            }
        }
        #pragma unroll
        for (int off = 1; off < 16; off <<= 1) {
            #pragma unroll
            for (int r = 0; r < 4; r++) rs[r] += __shfl_xor(rs[r], off);
        }
        #pragma unroll
        for (int r = 0; r < 4; r++) lrow[r] = lrow[r] * fac[r] + rs[r];
        #pragma unroll
        for (int dt = 0; dt < 4; dt++) {
            #pragma unroll
            for (int r = 0; r < 4; r++) od[dt][r] *= fac[r];
        }

        bf16x8 pf0 = *(const bf16x8*)(&Ps[16 * w + fr][fko]);
        bf16x8 pf1 = *(const bf16x8*)(&Ps[16 * w + fr][fko + 32]);
        #pragma unroll
        for (int dt = 0; dt < 4; dt++) {
            bf16x8 vf0 = *(const bf16x8*)(&Vt[dt * 16 + fr][fko]);
            bf16x8 vf1 = *(const bf16x8*)(&Vt[dt * 16 + fr][fko + 32]);
            od[dt] = __builtin_amdgcn_mfma_f32_16x16x32_bf16(pf0, vf0, od[dt], 0, 0, 0);
            od[dt] = __builtin_amdgcn_mfma_f32_16x16x32_bf16(pf1, vf1, od[dt], 0, 0, 0);
        }
    }

    #pragma unroll
    for (int r = 0; r < 4; r++) {
        int i = i0 + 16 * w + fq * 4 + r;
        if (i >= NTOK) continue;
        float inv = 1.0f / lrow[r];
        #pragma unroll
        for (int dt = 0; dt < 4; dt++) {
            obuf[((size_t)b * NTOK + i) * DIM + h * DH + dt * 16 + fr] = f2bf(od[dt][r] * inv);
        }
    }
}

// ---------------- bf16 MFMA GEMM, B^T weights: C = A @ Wt^T ----------------
template <int BM, int BN, int ACT, int OBF>
__global__ __launch_bounds__(256) void gemm_bt_kernel(const unsigned short* __restrict__ A,
                                                      const unsigned short* __restrict__ Bt,
                                                      const float* __restrict__ bias,
                                                      const float* __restrict__ resid,
                                                      void* __restrict__ Cv,
                                                      int M, int N, int K) {
    constexpr int FM = BM / 32, FN = BN / 32;
    __shared__ unsigned short Al[BM][72];
    __shared__ unsigned short Bl[BN][72];
    const int tid = threadIdx.x;
    const int bm = blockIdx.y * BM, bn = blockIdx.x * BN;
    const int wid = tid >> 6, lane = tid & 63;
    const int wr = (wid >> 1) * (BM / 2), wc = (wid & 1) * (BN / 2);
    const int fr = lane & 15, fko = (lane >> 4) * 8;
    const int srow = tid >> 3, sc8 = (tid & 7) * 8;

    f32x4 acc[FM][FN];
    #pragma unroll
    for (int m = 0; m < FM; m++)
        #pragma unroll
        for (int n = 0; n < FN; n++) acc[m][n] = (f32x4){0.f, 0.f, 0.f, 0.f};

    for (int kt = 0; kt < K; kt += 64) {
        #pragma unroll
        for (int q = 0; q < BM / 32; q++) {
            int r = srow + q * 32;
            int row = bm + r;
            u16x8 va = {0,0,0,0,0,0,0,0};
            if (row < M) va = *(const u16x8*)(A + (size_t)row * K + kt + sc8);
            *(u16x8*)(&Al[r][sc8]) = va;
        }
        #pragma unroll
        for (int q = 0; q < BN / 32; q++) {
            int r = srow + q * 32;
            u16x8 vb = *(const u16x8*)(Bt + (size_t)(bn + r) * K + kt + sc8);
            *(u16x8*)(&Bl[r][sc8]) = vb;
        }
        __syncthreads();
        #pragma unroll
        for (int ks = 0; ks < 2; ks++) {
            bf16x8 af[FM], bfr[FN];
            #pragma unroll
            for (int m = 0; m < FM; m++) af[m]  = *(const bf16x8*)(&Al[wr + m * 16 + fr][ks * 32 + fko]);
            #pragma unroll
            for (int n = 0; n < FN; n++) bfr[n] = *(const bf16x8*)(&Bl[wc + n * 16 + fr][ks * 32 + fko]);
            #pragma unroll
            for (int m = 0; m < FM; m++)
                #pragma unroll
                for (int n = 0; n < FN; n++)
                    acc[m][n] = __builtin_amdgcn_mfma_f32_16x16x32_bf16(af[m], bfr[n], acc[m][n], 0, 0, 0);
        }
        __syncthreads();
    }

    float* Cf = (float*)Cv;
    unsigned short* Cb = (unsigned short*)Cv;
    const int rg = (lane >> 4) * 4;
    #pragma unroll
    for (int m = 0; m < FM; m++) {
        #pragma unroll
        for (int n = 0; n < FN; n++) {
            int col = bn + wc + n * 16 + fr;
            float bv = bias ? bias[col] : 0.f;
            #pragma unroll
            for (int j = 0; j < 4; j++) {
                int row = bm + wr + m * 16 + rg + j;
                if (row >= M) continue;
                float v = acc[m][n][j] + bv;
                if (ACT == 1) v = 0.5f * v * (1.0f + erff(v * 0.70710678118654752f));
                if (resid) v += resid[(size_t)row * N + col];
                if (OBF) Cb[(size_t)row * N + col] = f2bf(v);
                else     Cf[(size_t)row * N + col] = v;
            }
        }
    }
}

__global__ void copyout_kernel(const float* __restrict__ x, float* __restrict__ out) {
    int t = blockIdx.x * 256 + threadIdx.x;
    if (t < 2 * DIM) {
        int b = t >> 9, d = t & 511;
        out[t] = x[(size_t)(b * NTOK) * DIM + d];
    }
}

// ---------------------------------------------------------------------------
extern "C" void kernel_launch(void* const* d_in, const int* in_sizes, int n_in,
                              void* d_out, int out_size, void* d_ws, size_t ws_size,
                              hipStream_t stream) {
    const float* f      = (const float*)d_in[0];
    const float* sa_w0  = (const float*)d_in[1];
    const float* sa_b0  = (const float*)d_in[2];
    const float* sa_w1  = (const float*)d_in[3];
    const float* sa_b1  = (const float*)d_in[4];
    const float* sa_w2  = (const float*)d_in[5];
    const float* sa_b2  = (const float*)d_in[6];
    const float* bn_g0  = (const float*)d_in[7];
    const float* bn_b0  = (const float*)d_in[8];
    const float* bn_m0  = (const float*)d_in[9];
    const float* bn_v0  = (const float*)d_in[10];
    const float* bn_g1  = (const float*)d_in[11];
    const float* bn_b1  = (const float*)d_in[12];
    const float* bn_m1  = (const float*)d_in[13];
    const float* bn_v1  = (const float*)d_in[14];
    const float* bn_g2  = (const float*)d_in[15];
    const float* bn_b2  = (const float*)d_in[16];
    const float* bn_m2  = (const float*)d_in[17];
    const float* bn_v2  = (const float*)d_in[18];
    const float* lift_w = (const float*)d_in[19];
    const float* lift_b = (const float*)d_in[20];
    const float* lift_g = (const float*)d_in[21];
    const float* lift_be= (const float*)d_in[22];
    const float* cls    = (const float*)d_in[23];
    const float* qkv_w  = (const float*)d_in[24];
    const float* out_w  = (const float*)d_in[25];
    const float* out_b  = (const float*)d_in[26];
    const float* ln1_g  = (const float*)d_in[27];
    const float* ln1_b  = (const float*)d_in[28];
    const float* pe_w1  = (const float*)d_in[29];
    const float* pe_b1  = (const float*)d_in[30];
    const float* pe_w2  = (const float*)d_in[31];
    const float* pe_b2  = (const float*)d_in[32];
    const float* ln2_g  = (const float*)d_in[33];
    const float* ln2_b  = (const float*)d_in[34];
    const float* ff_w1  = (const float*)d_in[35];
    const float* ff_b1  = (const float*)d_in[36];
    const float* ff_w2  = (const float*)d_in[37];
    const float* ff_b2  = (const float*)d_in[38];

    char* ws = (char*)d_ws;
    size_t off = 0;
    auto alloc = [&](size_t bytes) -> char* {
        char* p = ws + off;
        off = (off + bytes + 255) & ~(size_t)255;
        return p;
    };
    float* cent3 = (float*)alloc((size_t)2 * NTOK * 3 * 4);
    float* featb = (float*)alloc((size_t)2 * NP * SAD * 4);
    float* xbuf  = (float*)alloc((size_t)2 * NTOK * DIM * 4);
    unsigned short* h1buf = (unsigned short*)alloc((size_t)2 * NTOK * DIM * 2);
    unsigned short* qkvb  = (unsigned short*)alloc((size_t)2 * NTOK * 3 * DIM * 2);
    unsigned short* obuf  = (unsigned short*)alloc((size_t)2 * NTOK * DIM * 2);
    unsigned short* hff   = (unsigned short*)alloc((size_t)2 * NTOK * MLPD * 2);
    float* pebuf = (float*)alloc((size_t)DEPTH * 2 * NTOK * NTOK * 4);
    unsigned short* qkvT = (unsigned short*)alloc((size_t)DEPTH * 3 * DIM * DIM * 2);
    unsigned short* outT = (unsigned short*)alloc((size_t)DEPTH * DIM * DIM * 2);
    unsigned short* ff1T = (unsigned short*)alloc((size_t)DEPTH * DIM * MLPD * 2);
    unsigned short* ff2T = (unsigned short*)alloc((size_t)DEPTH * MLPD * DIM * 2);

    // FPS (2 blocks) + all weight conversion tiles (3072 blocks) in one launch
    fps_wconv_kernel<<<3074, 512, 0, stream>>>(f, cent3,
        qkv_w, qkvT, out_w, outT, ff_w1, ff1T, ff_w2, ff2T);
    // ballmlp (1024 blocks) + pe for all 6 layers (6*PEB blocks) in one launch
    ballmlp_pe_kernel<<<2 * NP + DEPTH * PEB, 256, 0, stream>>>(f, cent3,
        sa_w0, sa_b0, bn_g0, bn_b0, bn_m0, bn_v0,
        sa_w1, sa_b1, bn_g1, bn_b1, bn_m1, bn_v1,
        sa_w2, sa_b2, bn_g2, bn_b2, bn_m2, bn_v2, featb,
        pe_w1, pe_b1, pe_w2, pe_b2, pebuf);
    lift_ln_kernel<<<2 * NP + 2, 256, 0, stream>>>(cent3, featb, lift_w, lift_b, lift_g, lift_be, cls, xbuf);

    const int M = 2 * NTOK;   // 1026
    const int GY = (M + 63) / 64;   // 17
    const size_t peL = 2L * NTOK * NTOK;
    for (int l = 0; l < DEPTH; l++) {
        ln_kernel<<<M, 256, 0, stream>>>(xbuf, ln1_g + l * DIM, ln1_b + l * DIM, h1buf);
        gemm_bt_kernel<64, 64, 0, 1><<<dim3(24, GY), 256, 0, stream>>>(
            h1buf, qkvT + (size_t)l * 3 * DIM * DIM, nullptr, nullptr, qkvb, M, 3 * DIM, DIM);
        attn_mfma_kernel<<<dim3(9, 16), 256, 0, stream>>>(qkvb, pebuf + (size_t)l * peL, obuf);
        gemm_bt_kernel<64, 32, 0, 0><<<dim3(16, GY), 256, 0, stream>>>(
            obuf, outT + (size_t)l * DIM * DIM, out_b + l * DIM, xbuf, xbuf, M, DIM, DIM);
        ln_kernel<<<M, 256, 0, stream>>>(xbuf, ln2_g + l * DIM, ln2_b + l * DIM, h1buf);
        gemm_bt_kernel<64, 64, 1, 1><<<dim3(16, GY), 256, 0, stream>>>(
            h1buf, ff1T + (size_t)l * DIM * MLPD, ff_b1 + l * MLPD, nullptr, hff, M, MLPD, DIM);
        gemm_bt_kernel<64, 32, 0, 0><<<dim3(16, GY), 256, 0, stream>>>(
            hff, ff2T + (size_t)l * MLPD * DIM, ff_b2 + l * DIM, xbuf, xbuf, M, DIM, MLPD);
    }
    copyout_kernel<<<4, 256, 0, stream>>>(xbuf, (float*)d_out);
}

// Round 13
// 1332.805 us; speedup vs baseline: 1.0888x; 1.0888x over previous
//
#include <hip/hip_runtime.h>
#include <math.h>

#define NPTS 10000
#define NP   512    // npoint
#define NS   64     // nsample
#define NTOK 513    // 1 + NP
#define DIM  512
#define NHEADS 8
#define DH   64
#define DEPTH 6
#define SAD  256
#define MLPD 1024
#define EPSV 1e-5f
#define PEB  2057   // ceil(2*NTOK*NTOK / 256)

typedef float  f32x2  __attribute__((ext_vector_type(2)));
typedef float  f32x4  __attribute__((ext_vector_type(4)));
typedef __bf16 bf16x8 __attribute__((ext_vector_type(8)));
typedef unsigned short u16x4 __attribute__((ext_vector_type(4)));
typedef unsigned short u16x8 __attribute__((ext_vector_type(8)));

__device__ __forceinline__ unsigned short f2bf(float x) {
    unsigned u = __float_as_uint(x);
    unsigned r = u + 0x7fffu + ((u >> 16) & 1u);   // RNE
    return (unsigned short)(r >> 16);
}
__device__ __forceinline__ bf16x8 bf8_from_f32(const float* p) {
    u16x8 h;
    #pragma unroll
    for (int e = 0; e < 8; e++) h[e] = f2bf(p[e]);
    return *(bf16x8*)&h;
}

// ---------------- block reduce helper (256-thread blocks) ----------------
__device__ __forceinline__ float blk_sum256(float v, float* red) {
    #pragma unroll
    for (int off = 32; off; off >>= 1) v += __shfl_down(v, off);
    __syncthreads();
    if ((threadIdx.x & 63) == 0) red[threadIdx.x >> 6] = v;
    __syncthreads();
    return red[0] + red[1] + red[2] + red[3];
}

// ---------------- FPS (blocks 0,1) + weight convert (blocks 2+) ------------
// FPS with LDS-resident point cloud (120 KB): winner-coordinate lookup after
// the barrier is a ~120cy LDS broadcast instead of a dependent L2 chain
// (~300-900cy) -- the term common to all four prior 720-760us variants.
// Per-thread argmax tree + DPP wave reduce (lane 63), ONE barrier/iter.
__global__ __launch_bounds__(512, 1) void fps_wconv_kernel(
        const float* __restrict__ f, float* __restrict__ cent3,
        const float* __restrict__ qkv_w, unsigned short* __restrict__ qkvT,
        const float* __restrict__ out_w, unsigned short* __restrict__ outT,
        const float* __restrict__ ff_w1, unsigned short* __restrict__ ff1T,
        const float* __restrict__ ff_w2, unsigned short* __restrict__ ff2T) {
    #pragma clang fp contract(off)
    __shared__ union {
        struct {
            float pts[3 * 10240];              // lx | ly | lz (120 KB)
            unsigned long long spk[2][8];
        } fps;
        unsigned short tl[64][65];             // wconv transpose tile
    } sh;

    if (blockIdx.x >= 2) {
        // ---------- weight convert+transpose (64x64 tile, 512 thr) ----------
        int id = blockIdx.x - 2;
        const float* Ws; unsigned short* Wd; int K, N, tn, per;
        if (id < 1152)      { Ws = qkv_w; Wd = qkvT; K = 512;  N = 1536; tn = 24; per = 192; }
        else if (id < 1536) { id -= 1152; Ws = out_w; Wd = outT; K = 512; N = 512; tn = 8;  per = 64;  }
        else if (id < 2304) { id -= 1536; Ws = ff_w1; Wd = ff1T; K = 512; N = 1024; tn = 16; per = 128; }
        else                { id -= 2304; Ws = ff_w2; Wd = ff2T; K = 1024; N = 512; tn = 8;  per = 128; }
        const int l = id / per, rem = id % per;
        const int n0 = (rem % tn) * 64, k0 = (rem / tn) * 64;
        Ws += (size_t)l * K * N;
        Wd += (size_t)l * K * N;
        const int ty = threadIdx.x >> 4, c4 = (threadIdx.x & 15) * 4;   // ty 0..31
        #pragma unroll
        for (int i = 0; i < 2; i++) {
            int r = ty + 32 * i;
            f32x4 v = *(const f32x4*)(Ws + (size_t)(k0 + r) * N + n0 + c4);
            sh.tl[c4 + 0][r] = f2bf(v.x);
            sh.tl[c4 + 1][r] = f2bf(v.y);
            sh.tl[c4 + 2][r] = f2bf(v.z);
            sh.tl[c4 + 3][r] = f2bf(v.w);
        }
        __syncthreads();
        #pragma unroll
        for (int i = 0; i < 2; i++) {
            int r = ty + 32 * i;
            u16x4 hv = { sh.tl[r][c4], sh.tl[r][c4 + 1], sh.tl[r][c4 + 2], sh.tl[r][c4 + 3] };
            *(u16x4*)(Wd + (size_t)(n0 + r) * K + k0 + c4) = hv;
        }
        return;
    }

    // ---------- FPS ----------
    const int b = blockIdx.x;
    const float* fx = f + (size_t)b * 3 * NPTS;
    const float* fy = fx + NPTS;
    const float* fz = fx + 2 * NPTS;
    const int t = threadIdx.x;
    const int wv = t >> 6, lane = t & 63;

    float* lx = sh.fps.pts;
    float* ly = sh.fps.pts + 10240;
    float* lz = sh.fps.pts + 20480;
    for (int p = t; p < NPTS; p += 512) {
        lx[p] = fx[p]; ly[p] = fy[p]; lz[p] = fz[p];
    }

    f32x2 px[10], py[10], pz[10], dist[10];
    #pragma unroll
    for (int q = 0; q < 10; q++) {
        #pragma unroll
        for (int e = 0; e < 2; e++) {
            int p = t + (2 * q + e) * 512;
            if (p < NPTS) { px[q][e] = fx[p]; py[q][e] = fy[p]; pz[q][e] = fz[p]; dist[q][e] = 1e10f; }
            else          { px[q][e] = 0.f;  py[q][e] = 0.f;  pz[q][e] = 0.f;  dist[q][e] = -1.0f; }
        }
    }
    if (t == 0) {
        float* c0 = cent3 + (size_t)b * NTOK * 3;
        c0[0] = 0.f; c0[1] = 0.f; c0[2] = 0.f;
    }
    float cx = fx[0], cy = fy[0], cz = fz[0];
    __syncthreads();   // staging complete

    for (int it = 0; it < NP; ++it) {
        if (t == 0) {
            float* c = cent3 + (size_t)(b * NTOK + 1 + it) * 3;
            c[0] = cx; c[1] = cy; c[2] = cz;
        }
        const f32x2 c2x = {cx, cx}, c2y = {cy, cy}, c2z = {cz, cz};
        float av[20]; unsigned ai[20];
        #pragma unroll
        for (int q = 0; q < 10; q++) {
            f32x2 dx = px[q] - c2x;
            f32x2 dy = py[q] - c2y;
            f32x2 dz = pz[q] - c2z;
            f32x2 s1 = dx * dx;
            f32x2 s2 = dy * dy;
            f32x2 s3 = dz * dz;
            f32x2 d  = (s1 + s2) + s3;
            f32x2 nd = __builtin_elementwise_min(dist[q], d);
            dist[q] = nd;
            av[2 * q]     = nd.x; ai[2 * q]     = (unsigned)(t + (2 * q) * 512);
            av[2 * q + 1] = nd.y; ai[2 * q + 1] = (unsigned)(t + (2 * q + 1) * 512);
        }
        // in-thread argmax tree; slots ordered by index so '>' keeps first-max
        #define CMB(a, bq) if (av[bq] > av[a]) { av[a] = av[bq]; ai[a] = ai[bq]; }
        #pragma unroll
        for (int i = 0; i < 10; i++) CMB(i, i + 10)
        #pragma unroll
        for (int i = 0; i < 5; i++) CMB(i, i + 5)
        CMB(0, 1) CMB(2, 3) CMB(0, 2) CMB(0, 4)
        #undef CMB
        float bv = av[0]; unsigned bi = ai[0];
        // wave argmax via DPP (lexicographic: larger dist, then smaller idx)
        #define DSTEP(CTRL, RM) { \
            int _ov = __builtin_amdgcn_update_dpp(__float_as_int(bv), __float_as_int(bv), CTRL, RM, 0xF, false); \
            int _oi = __builtin_amdgcn_update_dpp((int)bi, (int)bi, CTRL, RM, 0xF, false); \
            float ov = __int_as_float(_ov); unsigned oi = (unsigned)_oi; \
            bool take = (ov > bv) || (ov == bv && oi < bi); \
            bv = take ? ov : bv; bi = take ? oi : bi; \
        }
        DSTEP(0x111, 0xF)   // row_shr:1
        DSTEP(0x112, 0xF)   // row_shr:2
        DSTEP(0x114, 0xF)   // row_shr:4
        DSTEP(0x118, 0xF)   // row_shr:8
        DSTEP(0x142, 0xA)   // row_bcast:15 -> rows 1,3
        DSTEP(0x143, 0xC)   // row_bcast:31 -> rows 2,3
        #undef DSTEP
        const int cur = it & 1;
        if (lane == 63) {
            sh.fps.spk[cur][wv] = ((unsigned long long)__float_as_uint(bv) << 32)
                                | (unsigned long long)(~bi);
        }
        __syncthreads();
        unsigned long long g = sh.fps.spk[cur][0];
        #pragma unroll
        for (int w = 1; w < 8; w++) {
            unsigned long long o = sh.fps.spk[cur][w];
            g = (o > g) ? o : g;
        }
        const unsigned widx = ~(unsigned)g;
        cx = lx[widx]; cy = ly[widx]; cz = lz[widx];   // LDS broadcast (~120cy)
    }
}

// ---------------- ballmlp (blocks < 2*NP) + pe bias (blocks >= 2*NP) --------
__global__ __launch_bounds__(256) void ballmlp_pe_kernel(
        const float* __restrict__ f, const float* __restrict__ cent3,
        const float* __restrict__ w0, const float* __restrict__ b0,
        const float* __restrict__ g0, const float* __restrict__ be0,
        const float* __restrict__ m0, const float* __restrict__ v0,
        const float* __restrict__ w1, const float* __restrict__ b1,
        const float* __restrict__ g1, const float* __restrict__ be1,
        const float* __restrict__ m1, const float* __restrict__ v1,
        const float* __restrict__ w2, const float* __restrict__ b2,
        const float* __restrict__ g2, const float* __restrict__ be2,
        const float* __restrict__ m2, const float* __restrict__ v2,
        float* __restrict__ featb,
        const float* __restrict__ pw1_, const float* __restrict__ pb1_,
        const float* __restrict__ pw2_, const float* __restrict__ pb2_,
        float* __restrict__ pebuf) {
    if (blockIdx.x >= 2 * NP) {
        // ---------- pe bias: fused 3->64(relu)->1, all layers ----------
        const int id = blockIdx.x - 2 * NP;
        const int l = id / PEB, rem = id % PEB;
        const float* pw1 = pw1_ + l * 192;
        const float* pb1 = pb1_ + l * 64;
        const float* pw2 = pw2_ + l * 64;
        const long total = 2L * NTOK * NTOK;
        long gid = (long)rem * 256 + threadIdx.x;
        if (gid >= total) return;
        int j = (int)(gid % NTOK);
        long r = gid / NTOK;
        int i = (int)(r % NTOK);
        int b = (int)(r / NTOK);
        const float* ci = cent3 + (size_t)(b * NTOK + i) * 3;
        const float* cj = cent3 + (size_t)(b * NTOK + j) * 3;
        float d0 = ci[0] - cj[0], d1 = ci[1] - cj[1], d2 = ci[2] - cj[2];
        float acc = pb2_[l];
        #pragma unroll 8
        for (int c = 0; c < 64; c++) {
            float tv = pw1[c * 3] * d0 + pw1[c * 3 + 1] * d1 + pw1[c * 3 + 2] * d2 + pb1[c];
            acc += pw2[c] * fmaxf(tv, 0.f);
        }
        pebuf[(size_t)l * total + gid] = acc;
        return;
    }

    // ---------- ballmlp ----------
    const int bs = blockIdx.x;
    const int b = bs / NP, s = bs % NP;
    const int tid = threadIdx.x;
    const int wv = tid >> 6, lane = tid & 63;
    const int fr = lane & 15, fq = lane >> 4;

    __shared__ int sidx[NS];
    __shared__ alignas(16) unsigned short Xl[64][8];
    __shared__ alignas(16) unsigned short H1[64][72];
    __shared__ alignas(16) unsigned short H2[64][72];

    const float* fx = f + (size_t)b * 3 * NPTS;
    const float* fy = fx + NPTS;
    const float* fz = fx + 2 * NPTS;
    const float* c  = cent3 + (size_t)(b * NTOK + 1 + s) * 3;
    const float nx = c[0], ny = c[1], nz = c[2];

    const int c1 = 16 * wv + fr;
    const float sc0 = g0[c1] / sqrtf(v0[c1] + EPSV);
    const float off0 = (b0[c1] - m0[c1]) * sc0 + be0[c1];
    const float sc1 = g1[c1] / sqrtf(v1[c1] + EPSV);
    const float off1 = (b1[c1] - m1[c1]) * sc1 + be1[c1];

    u16x8 b0h = {0,0,0,0,0,0,0,0};
    if (fq == 0) {
        const float* wr = w0 + c1 * 6;
        #pragma unroll
        for (int e = 0; e < 6; e++) b0h[e] = f2bf(wr[e]);
    }
    bf16x8 bf0 = *(bf16x8*)&b0h;
    bf16x8 bf1[2];
    #pragma unroll
    for (int ks = 0; ks < 2; ks++)
        bf1[ks] = bf8_from_f32(w1 + (size_t)c1 * 64 + ks * 32 + fq * 8);

    if (wv == 0) {
        const float nn = __fadd_rn(__fadd_rn(__fmul_rn(nx, nx), __fmul_rn(ny, ny)), __fmul_rn(nz, nz));
        int cnt = 0, first = -1;
        for (int base = 0; base < NPTS; base += 64) {
            const int p = base + lane;
            bool valid = false;
            if (p < NPTS) {
                float x = fx[p], y = fy[p], z = fz[p];
                float pp = __fadd_rn(__fadd_rn(__fmul_rn(x, x), __fmul_rn(y, y)), __fmul_rn(z, z));
                float dt = __fadd_rn(__fadd_rn(__fmul_rn(nx, x), __fmul_rn(ny, y)), __fmul_rn(nz, z));
                float sq = __fsub_rn(__fadd_rn(nn, pp), __fmul_rn(2.0f, dt));
                valid = !(sq > 0.04f);
            }
            unsigned long long m = __ballot(valid);
            if (first < 0 && m) first = base + __builtin_ctzll(m);
            int pos = cnt + __popcll(m & ((1ull << lane) - 1ull));
            if (valid && pos < NS) sidx[pos] = p;
            cnt += __popcll(m);
            if (cnt >= NS) break;
        }
        for (int pos = cnt + lane; pos < NS; pos += 64) sidx[pos] = first;
    }
    __syncthreads();

    if (tid < 64) {
        const int p = sidx[tid];
        float i3 = fx[p], i4 = fy[p], i5 = fz[p];
        u16x8 xv;
        xv[0] = f2bf(i3 - nx); xv[1] = f2bf(i4 - ny); xv[2] = f2bf(i5 - nz);
        xv[3] = f2bf(i3); xv[4] = f2bf(i4); xv[5] = f2bf(i5);
        xv[6] = 0; xv[7] = 0;
        *(u16x8*)(&Xl[tid][0]) = xv;
    }
    __syncthreads();

    const u16x8 z8 = {0,0,0,0,0,0,0,0};
    const bf16x8 zf = *(const bf16x8*)&z8;

    #pragma unroll
    for (int m = 0; m < 4; m++) {
        bf16x8 af = (fq == 0) ? *(const bf16x8*)(&Xl[m * 16 + fr][0]) : zf;
        f32x4 d = (f32x4){0.f, 0.f, 0.f, 0.f};
        d = __builtin_amdgcn_mfma_f32_16x16x32_bf16(af, bf0, d, 0, 0, 0);
        #pragma unroll
        for (int j = 0; j < 4; j++) {
            float v = fmaxf(d[j] * sc0 + off0, 0.f);
            H1[m * 16 + fq * 4 + j][16 * wv + fr] = f2bf(v);
        }
    }
    __syncthreads();

    #pragma unroll
    for (int m = 0; m < 4; m++) {
        f32x4 d = (f32x4){0.f, 0.f, 0.f, 0.f};
        #pragma unroll
        for (int ks = 0; ks < 2; ks++) {
            bf16x8 af = *(const bf16x8*)(&H1[m * 16 + fr][ks * 32 + fq * 8]);
            d = __builtin_amdgcn_mfma_f32_16x16x32_bf16(af, bf1[ks], d, 0, 0, 0);
        }
        #pragma unroll
        for (int j = 0; j < 4; j++) {
            float v = fmaxf(d[j] * sc1 + off1, 0.f);
            H2[m * 16 + fq * 4 + j][16 * wv + fr] = f2bf(v);
        }
    }
    __syncthreads();

    bf16x8 af2[4][2];
    #pragma unroll
    for (int m = 0; m < 4; m++)
        #pragma unroll
        for (int ks = 0; ks < 2; ks++)
            af2[m][ks] = *(const bf16x8*)(&H2[m * 16 + fr][ks * 32 + fq * 8]);

    float* outp = featb + (size_t)bs * SAD;
    #pragma unroll
    for (int t = 0; t < 4; t++) {
        const int c2 = 64 * wv + 16 * t + fr;
        const float sc2 = g2[c2] / sqrtf(v2[c2] + EPSV);
        const float off2 = (b2[c2] - m2[c2]) * sc2 + be2[c2];
        bf16x8 bf2[2];
        #pragma unroll
        for (int ks = 0; ks < 2; ks++)
            bf2[ks] = bf8_from_f32(w2 + (size_t)c2 * 64 + ks * 32 + fq * 8);
        float mx = -INFINITY;
        #pragma unroll
        for (int m = 0; m < 4; m++) {
            f32x4 d = (f32x4){0.f, 0.f, 0.f, 0.f};
            d = __builtin_amdgcn_mfma_f32_16x16x32_bf16(af2[m][0], bf2[0], d, 0, 0, 0);
            d = __builtin_amdgcn_mfma_f32_16x16x32_bf16(af2[m][1], bf2[1], d, 0, 0, 0);
            #pragma unroll
            for (int j = 0; j < 4; j++)
                mx = fmaxf(mx, fmaxf(d[j] * sc2 + off2, 0.f));
        }
        mx = fmaxf(mx, __shfl_xor(mx, 16));
        mx = fmaxf(mx, __shfl_xor(mx, 32));
        if (fq == 0) outp[c2] = mx;
    }
}

// ---------------- lift (259->512) + LayerNorm (+cls rows, blocks 0,1) -------
__global__ __launch_bounds__(256) void lift_ln_kernel(const float* __restrict__ cent3,
                                                      const float* __restrict__ featb,
                                                      const float* __restrict__ lw,
                                                      const float* __restrict__ lb,
                                                      const float* __restrict__ lg,
                                                      const float* __restrict__ lbeta,
                                                      const float* __restrict__ cls,
                                                      float* __restrict__ x) {
    const int t = threadIdx.x;
    if (blockIdx.x < 2) {
        int b = blockIdx.x;
        x[(size_t)(b * NTOK) * DIM + t]       = cls[t];
        x[(size_t)(b * NTOK) * DIM + t + 256] = cls[t + 256];
        return;
    }
    const int bs = blockIdx.x - 2;
    const int b = bs / NP, s = bs % NP;
    __shared__ float si[259];
    __shared__ float sy[512];
    __shared__ float red[4];
    if (t < 3) si[t] = cent3[(size_t)(b * NTOK + 1 + s) * 3 + t];
    si[3 + t] = featb[(size_t)bs * SAD + t];
    __syncthreads();
    for (int o = t; o < DIM; o += 256) {
        const float* wr = lw + (size_t)o * 259;
        float acc = lb[o];
        for (int ci = 0; ci < 259; ci++) acc += wr[ci] * si[ci];
        sy[o] = acc;
    }
    __syncthreads();
    float tot  = blk_sum256(sy[t] + sy[t + 256], red);
    float mean = tot * (1.0f / 512.0f);
    float d0 = sy[t] - mean, d1 = sy[t + 256] - mean;
    float var = blk_sum256(d0 * d0 + d1 * d1, red) * (1.0f / 512.0f);
    float inv = 1.0f / sqrtf(var + EPSV);
    float* xr = x + (size_t)(b * NTOK + 1 + s) * DIM;
    xr[t]       = d0 * inv * lg[t]       + lbeta[t];
    xr[t + 256] = d1 * inv * lg[t + 256] + lbeta[t + 256];
}

// ---------------- LayerNorm rows of [2*NTOK, 512]; bf16 output --------------
__global__ __launch_bounds__(256) void ln_kernel(const float* __restrict__ xin,
                                                 const float* __restrict__ g,
                                                 const float* __restrict__ beta,
                                                 unsigned short* __restrict__ y) {
    const int r = blockIdx.x;
    const float* xr = xin + (size_t)r * DIM;
    const int t = threadIdx.x;
    float a0 = xr[t], a1 = xr[t + 256];
    __shared__ float red[4];
    float mean = blk_sum256(a0 + a1, red) * (1.0f / 512.0f);
    float d0 = a0 - mean, d1 = a1 - mean;
    float var = blk_sum256(d0 * d0 + d1 * d1, red) * (1.0f / 512.0f);
    float inv = 1.0f / sqrtf(var + EPSV);
    unsigned short* yr = y + (size_t)r * DIM;
    yr[t]       = f2bf(d0 * inv * g[t]       + beta[t]);
    yr[t + 256] = f2bf(d1 * inv * g[t + 256] + beta[t + 256]);
}

// ---------------- MFMA flash attention (bf16 qkv in, bf16 out) --------------
__global__ __launch_bounds__(256) void attn_mfma_kernel(const unsigned short* __restrict__ qkv,
                                                        const float* __restrict__ pebuf,
                                                        unsigned short* __restrict__ obuf) {
    __shared__ alignas(16) unsigned short Qs[64][72];
    __shared__ alignas(16) unsigned short Ks[64][72];
    __shared__ alignas(16) unsigned short Vt[64][72];
    __shared__ alignas(16) unsigned short Ps[64][72];

    const int ti = blockIdx.x;           // 0..8
    const int bh = blockIdx.y;           // 0..15
    const int b = bh >> 3, h = bh & 7;
    const int i0 = ti * 64;
    const int tid = threadIdx.x;
    const int w = tid >> 6, lane = tid & 63;
    const int fr = lane & 15, fq = lane >> 4;
    const int fko = fq * 8;

    const unsigned short* qbase = qkv + (size_t)b * NTOK * (3 * DIM) + h * DH;
    const int sr = tid >> 2, sc = (tid & 3) * 16;

    {
        int i = i0 + sr;
        u16x8 v0 = {0,0,0,0,0,0,0,0}, v1 = {0,0,0,0,0,0,0,0};
        if (i < NTOK) {
            v0 = *(const u16x8*)(qbase + (size_t)i * (3 * DIM) + sc);
            v1 = *(const u16x8*)(qbase + (size_t)i * (3 * DIM) + sc + 8);
        }
        *(u16x8*)(&Qs[sr][sc]) = v0;
        *(u16x8*)(&Qs[sr][sc + 8]) = v1;
    }

    float mrow[4], lrow[4];
    f32x4 od[4];
    #pragma unroll
    for (int r = 0; r < 4; r++) { mrow[r] = -INFINITY; lrow[r] = 0.f; }
    #pragma unroll
    for (int dt = 0; dt < 4; dt++) od[dt] = (f32x4){0.f, 0.f, 0.f, 0.f};

    const unsigned short* kbase = qkv + (size_t)b * NTOK * (3 * DIM) + DIM + h * DH;
    const unsigned short* vbase = qkv + (size_t)b * NTOK * (3 * DIM) + 2 * DIM + h * DH;

    for (int jc = 0; jc < 9; jc++) {
        const int j0 = jc * 64;
        const int wj = (NTOK - j0) < 64 ? (NTOK - j0) : 64;   // 64 or 1
        __syncthreads();
        if (sr < wj) {
            const unsigned short* kp = kbase + (size_t)(j0 + sr) * (3 * DIM) + sc;
            const unsigned short* vp = vbase + (size_t)(j0 + sr) * (3 * DIM) + sc;
            u16x8 k0 = *(const u16x8*)(kp);
            u16x8 k1 = *(const u16x8*)(kp + 8);
            *(u16x8*)(&Ks[sr][sc]) = k0;
            *(u16x8*)(&Ks[sr][sc + 8]) = k1;
            u16x8 q0 = *(const u16x8*)(vp);
            u16x8 q1 = *(const u16x8*)(vp + 8);
            #pragma unroll
            for (int e = 0; e < 8; e++) {
                Vt[sc + e][sr] = q0[e];
                Vt[sc + 8 + e][sr] = q1[e];
            }
        } else {
            u16x8 z = {0,0,0,0,0,0,0,0};
            *(u16x8*)(&Ks[sr][sc]) = z;
            *(u16x8*)(&Ks[sr][sc + 8]) = z;
            #pragma unroll
            for (int e = 0; e < 16; e++) Vt[sc + e][sr] = 0;
        }
        __syncthreads();

        bf16x8 qf0 = *(const bf16x8*)(&Qs[16 * w + fr][fko]);
        bf16x8 qf1 = *(const bf16x8*)(&Qs[16 * w + fr][fko + 32]);
        f32x4 sa[4];
        #pragma unroll
        for (int jt = 0; jt < 4; jt++) {
            f32x4 acc = (f32x4){0.f, 0.f, 0.f, 0.f};
            bf16x8 kf0 = *(const bf16x8*)(&Ks[jt * 16 + fr][fko]);
            bf16x8 kf1 = *(const bf16x8*)(&Ks[jt * 16 + fr][fko + 32]);
            acc = __builtin_amdgcn_mfma_f32_16x16x32_bf16(qf0, kf0, acc, 0, 0, 0);
            acc = __builtin_amdgcn_mfma_f32_16x16x32_bf16(qf1, kf1, acc, 0, 0, 0);
            sa[jt] = acc;
        }

        float sv[4][4];
        float cm[4] = {-INFINITY, -INFINITY, -INFINITY, -INFINITY};
        #pragma unroll
        for (int jt = 0; jt < 4; jt++) {
            int jl = jt * 16 + fr;
            int jg = j0 + jl; if (jg > NTOK - 1) jg = NTOK - 1;
            #pragma unroll
            for (int r = 0; r < 4; r++) {
                int i = i0 + 16 * w + fq * 4 + r; if (i > NTOK - 1) i = NTOK - 1;
                float pe = pebuf[((size_t)b * NTOK + i) * NTOK + jg];
                float s = (sa[jt][r] + pe) * 0.125f;
                s = (jl < wj) ? s : -INFINITY;
                sv[jt][r] = s;
                cm[r] = fmaxf(cm[r], s);
            }
        }
        #pragma unroll
        for (int off = 1; off < 16; off <<= 1) {
            #pragma unroll
            for (int r = 0; r < 4; r++) cm[r] = fmaxf(cm[r], __shfl_xor(cm[r], off));
        }
        float fac[4], rs[4];
        #pragma unroll
        for (int r = 0; r < 4; r++) {
            float mn = fmaxf(mrow[r], cm[r]);
            fac[r] = __expf(mrow[r] - mn);
            mrow[r] = mn;
            rs[r] = 0.f;
        }
        #pragma unroll
        for (int jt = 0; jt < 4; jt++) {
            #pragma unroll
            for (int r = 0; r < 4; r++) {
                float p = __expf(sv[jt][r] - mrow[r]);
                rs[r] += p;
                Ps[16 * w + fq * 4 + r][jt * 16 + fr] = f2bf(p);
            }
        }
        #pragma unroll
        for (int off = 1; off < 16; off <<= 1) {
            #pragma unroll
            for (int r = 0; r < 4; r++) rs[r] += __shfl_xor(rs[r], off);
        }
        #pragma unroll
        for (int r = 0; r < 4; r++) lrow[r] = lrow[r] * fac[r] + rs[r];
        #pragma unroll
        for (int dt = 0; dt < 4; dt++) {
            #pragma unroll
            for (int r = 0; r < 4; r++) od[dt][r] *= fac[r];
        }

        bf16x8 pf0 = *(const bf16x8*)(&Ps[16 * w + fr][fko]);
        bf16x8 pf1 = *(const bf16x8*)(&Ps[16 * w + fr][fko + 32]);
        #pragma unroll
        for (int dt = 0; dt < 4; dt++) {
            bf16x8 vf0 = *(const bf16x8*)(&Vt[dt * 16 + fr][fko]);
            bf16x8 vf1 = *(const bf16x8*)(&Vt[dt * 16 + fr][fko + 32]);
            od[dt] = __builtin_amdgcn_mfma_f32_16x16x32_bf16(pf0, vf0, od[dt], 0, 0, 0);
            od[dt] = __builtin_amdgcn_mfma_f32_16x16x32_bf16(pf1, vf1, od[dt], 0, 0, 0);
        }
    }

    #pragma unroll
    for (int r = 0; r < 4; r++) {
        int i = i0 + 16 * w + fq * 4 + r;
        if (i >= NTOK) continue;
        float inv = 1.0f / lrow[r];
        #pragma unroll
        for (int dt = 0; dt < 4; dt++) {
            obuf[((size_t)b * NTOK + i) * DIM + h * DH + dt * 16 + fr] = f2bf(od[dt][r] * inv);
        }
    }
}

// ---------------- bf16 MFMA GEMM, B^T weights: C = A @ Wt^T ----------------
template <int BM, int BN, int ACT, int OBF>
__global__ __launch_bounds__(256) void gemm_bt_kernel(const unsigned short* __restrict__ A,
                                                      const unsigned short* __restrict__ Bt,
                                                      const float* __restrict__ bias,
                                                      const float* __restrict__ resid,
                                                      void* __restrict__ Cv,
                                                      int M, int N, int K) {
    constexpr int FM = BM / 32, FN = BN / 32;
    __shared__ unsigned short Al[BM][72];
    __shared__ unsigned short Bl[BN][72];
    const int tid = threadIdx.x;
    const int bm = blockIdx.y * BM, bn = blockIdx.x * BN;
    const int wid = tid >> 6, lane = tid & 63;
    const int wr = (wid >> 1) * (BM / 2), wc = (wid & 1) * (BN / 2);
    const int fr = lane & 15, fko = (lane >> 4) * 8;
    const int srow = tid >> 3, sc8 = (tid & 7) * 8;

    f32x4 acc[FM][FN];
    #pragma unroll
    for (int m = 0; m < FM; m++)
        #pragma unroll
        for (int n = 0; n < FN; n++) acc[m][n] = (f32x4){0.f, 0.f, 0.f, 0.f};

    for (int kt = 0; kt < K; kt += 64) {
        #pragma unroll
        for (int q = 0; q < BM / 32; q++) {
            int r = srow + q * 32;
            int row = bm + r;
            u16x8 va = {0,0,0,0,0,0,0,0};
            if (row < M) va = *(const u16x8*)(A + (size_t)row * K + kt + sc8);
            *(u16x8*)(&Al[r][sc8]) = va;
        }
        #pragma unroll
        for (int q = 0; q < BN / 32; q++) {
            int r = srow + q * 32;
            u16x8 vb = *(const u16x8*)(Bt + (size_t)(bn + r) * K + kt + sc8);
            *(u16x8*)(&Bl[r][sc8]) = vb;
        }
        __syncthreads();
        #pragma unroll
        for (int ks = 0; ks < 2; ks++) {
            bf16x8 af[FM], bfr[FN];
            #pragma unroll
            for (int m = 0; m < FM; m++) af[m]  = *(const bf16x8*)(&Al[wr + m * 16 + fr][ks * 32 + fko]);
            #pragma unroll
            for (int n = 0; n < FN; n++) bfr[n] = *(const bf16x8*)(&Bl[wc + n * 16 + fr][ks * 32 + fko]);
            #pragma unroll
            for (int m = 0; m < FM; m++)
                #pragma unroll
                for (int n = 0; n < FN; n++)
                    acc[m][n] = __builtin_amdgcn_mfma_f32_16x16x32_bf16(af[m], bfr[n], acc[m][n], 0, 0, 0);
        }
        __syncthreads();
    }

    float* Cf = (float*)Cv;
    unsigned short* Cb = (unsigned short*)Cv;
    const int rg = (lane >> 4) * 4;
    #pragma unroll
    for (int m = 0; m < FM; m++) {
        #pragma unroll
        for (int n = 0; n < FN; n++) {
            int col = bn + wc + n * 16 + fr;
            float bv = bias ? bias[col] : 0.f;
            #pragma unroll
            for (int j = 0; j < 4; j++) {
                int row = bm + wr + m * 16 + rg + j;
                if (row >= M) continue;
                float v = acc[m][n][j] + bv;
                if (ACT == 1) v = 0.5f * v * (1.0f + erff(v * 0.70710678118654752f));
                if (resid) v += resid[(size_t)row * N + col];
                if (OBF) Cb[(size_t)row * N + col] = f2bf(v);
                else     Cf[(size_t)row * N + col] = v;
            }
        }
    }
}

__global__ void copyout_kernel(const float* __restrict__ x, float* __restrict__ out) {
    int t = blockIdx.x * 256 + threadIdx.x;
    if (t < 2 * DIM) {
        int b = t >> 9, d = t & 511;
        out[t] = x[(size_t)(b * NTOK) * DIM + d];
    }
}

// ---------------------------------------------------------------------------
extern "C" void kernel_launch(void* const* d_in, const int* in_sizes, int n_in,
                              void* d_out, int out_size, void* d_ws, size_t ws_size,
                              hipStream_t stream) {
    const float* f      = (const float*)d_in[0];
    const float* sa_w0  = (const float*)d_in[1];
    const float* sa_b0  = (const float*)d_in[2];
    const float* sa_w1  = (const float*)d_in[3];
    const float* sa_b1  = (const float*)d_in[4];
    const float* sa_w2  = (const float*)d_in[5];
    const float* sa_b2  = (const float*)d_in[6];
    const float* bn_g0  = (const float*)d_in[7];
    const float* bn_b0  = (const float*)d_in[8];
    const float* bn_m0  = (const float*)d_in[9];
    const float* bn_v0  = (const float*)d_in[10];
    const float* bn_g1  = (const float*)d_in[11];
    const float* bn_b1  = (const float*)d_in[12];
    const float* bn_m1  = (const float*)d_in[13];
    const float* bn_v1  = (const float*)d_in[14];
    const float* bn_g2  = (const float*)d_in[15];
    const float* bn_b2  = (const float*)d_in[16];
    const float* bn_m2  = (const float*)d_in[17];
    const float* bn_v2  = (const float*)d_in[18];
    const float* lift_w = (const float*)d_in[19];
    const float* lift_b = (const float*)d_in[20];
    const float* lift_g = (const float*)d_in[21];
    const float* lift_be= (const float*)d_in[22];
    const float* cls    = (const float*)d_in[23];
    const float* qkv_w  = (const float*)d_in[24];
    const float* out_w  = (const float*)d_in[25];
    const float* out_b  = (const float*)d_in[26];
    const float* ln1_g  = (const float*)d_in[27];
    const float* ln1_b  = (const float*)d_in[28];
    const float* pe_w1  = (const float*)d_in[29];
    const float* pe_b1  = (const float*)d_in[30];
    const float* pe_w2  = (const float*)d_in[31];
    const float* pe_b2  = (const float*)d_in[32];
    const float* ln2_g  = (const float*)d_in[33];
    const float* ln2_b  = (const float*)d_in[34];
    const float* ff_w1  = (const float*)d_in[35];
    const float* ff_b1  = (const float*)d_in[36];
    const float* ff_w2  = (const float*)d_in[37];
    const float* ff_b2  = (const float*)d_in[38];

    char* ws = (char*)d_ws;
    size_t off = 0;
    auto alloc = [&](size_t bytes) -> char* {
        char* p = ws + off;
        off = (off + bytes + 255) & ~(size_t)255;
        return p;
    };
    float* cent3 = (float*)alloc((size_t)2 * NTOK * 3 * 4);
    float* featb = (float*)alloc((size_t)2 * NP * SAD * 4);
    float* xbuf  = (float*)alloc((size_t)2 * NTOK * DIM * 4);
    unsigned short* h1buf = (unsigned short*)alloc((size_t)2 * NTOK * DIM * 2);
    unsigned short* qkvb  = (unsigned short*)alloc((size_t)2 * NTOK * 3 * DIM * 2);
    unsigned short* obuf  = (unsigned short*)alloc((size_t)2 * NTOK * DIM * 2);
    unsigned short* hff   = (unsigned short*)alloc((size_t)2 * NTOK * MLPD * 2);
    float* pebuf = (float*)alloc((size_t)DEPTH * 2 * NTOK * NTOK * 4);
    unsigned short* qkvT = (unsigned short*)alloc((size_t)DEPTH * 3 * DIM * DIM * 2);
    unsigned short* outT = (unsigned short*)alloc((size_t)DEPTH * DIM * DIM * 2);
    unsigned short* ff1T = (unsigned short*)alloc((size_t)DEPTH * DIM * MLPD * 2);
    unsigned short* ff2T = (unsigned short*)alloc((size_t)DEPTH * MLPD * DIM * 2);

    // FPS (2 blocks) + all weight conversion tiles (3072 blocks) in one launch
    fps_wconv_kernel<<<3074, 512, 0, stream>>>(f, cent3,
        qkv_w, qkvT, out_w, outT, ff_w1, ff1T, ff_w2, ff2T);
    // ballmlp (1024 blocks) + pe for all 6 layers (6*PEB blocks) in one launch
    ballmlp_pe_kernel<<<2 * NP + DEPTH * PEB, 256, 0, stream>>>(f, cent3,
        sa_w0, sa_b0, bn_g0, bn_b0, bn_m0, bn_v0,
        sa_w1, sa_b1, bn_g1, bn_b1, bn_m1, bn_v1,
        sa_w2, sa_b2, bn_g2, bn_b2, bn_m2, bn_v2, featb,
        pe_w1, pe_b1, pe_w2, pe_b2, pebuf);
    lift_ln_kernel<<<2 * NP + 2, 256, 0, stream>>>(cent3, featb, lift_w, lift_b, lift_g, lift_be, cls, xbuf);

    const int M = 2 * NTOK;   // 1026
    const int GY = (M + 63) / 64;   // 17
    const size_t peL = 2L * NTOK * NTOK;
    for (int l = 0; l < DEPTH; l++) {
        ln_kernel<<<M, 256, 0, stream>>>(xbuf, ln1_g + l * DIM, ln1_b + l * DIM, h1buf);
        gemm_bt_kernel<64, 64, 0, 1><<<dim3(24, GY), 256, 0, stream>>>(
            h1buf, qkvT + (size_t)l * 3 * DIM * DIM, nullptr, nullptr, qkvb, M, 3 * DIM, DIM);
        attn_mfma_kernel<<<dim3(9, 16), 256, 0, stream>>>(qkvb, pebuf + (size_t)l * peL, obuf);
        gemm_bt_kernel<64, 32, 0, 0><<<dim3(16, GY), 256, 0, stream>>>(
            obuf, outT + (size_t)l * DIM * DIM, out_b + l * DIM, xbuf, xbuf, M, DIM, DIM);
        ln_kernel<<<M, 256, 0, stream>>>(xbuf, ln2_g + l * DIM, ln2_b + l * DIM, h1buf);
        gemm_bt_kernel<64, 64, 1, 1><<<dim3(16, GY), 256, 0, stream>>>(
            h1buf, ff1T + (size_t)l * DIM * MLPD, ff_b1 + l * MLPD, nullptr, hff, M, MLPD, DIM);
        gemm_bt_kernel<64, 32, 0, 0><<<dim3(16, GY), 256, 0, stream>>>(
            hff, ff2T + (size_t)l * MLPD * DIM, ff_b2 + l * DIM, xbuf, xbuf, M, DIM, MLPD);
    }
    copyout_kernel<<<4, 256, 0, stream>>>(xbuf, (float*)d_out);
}